// Round 12
// baseline (687.291 us; speedup 1.0000x reference)
//
#include <hip/hip_runtime.h>
#include <hip/hip_cooperative_groups.h>

namespace cg = cooperative_groups;

#define HDIM 128
#define OFF_SPECIAL 2
#define BSTRIDE 48   // bucket slots per node; deg~Poisson(16), P(deg>=48)~5e-11

typedef __attribute__((ext_vector_type(8))) short bf16x8;
typedef __attribute__((ext_vector_type(4))) float f32x4;
typedef __attribute__((ext_vector_type(2))) float f32x2;

__device__ __forceinline__ float bf2f(unsigned short u) {
    union { unsigned int i; float f; } v;
    v.i = ((unsigned int)u) << 16;
    return v.f;
}
__device__ __forceinline__ unsigned short f2bf(float f) {
    union { float f; unsigned int i; } v;
    v.f = f;
    unsigned int x = v.i;
    x += 0x7FFFu + ((x >> 16) & 1u);   // RNE; data has no NaNs
    return (unsigned short)(x >> 16);
}

// Scale folding for the fp8 emb cast: embf8 = q(16*emb). ReLU is positively
// homogeneous, so conv1 yields 16h (bias*16); conv2's agg2 is 16-scaled and
// the out phase applies acc*(1/16) + b1 directly (exact power-of-2 folding).
#define XSCALE 16.0f
#define XINV   0.0625f

// --- radix-partition CSR build (R7/R11-proven): ZERO global atomics.
#define SEG 500
#define PSTRIDE 48    // per-(wg,seg) bucket cap; Poisson(12.5), P(ovf)~1e-13
#define PART_W 256
#define CAST_BLOCKS 128   // x1024 threads
#define FLAG_BLOCKS 4

// riders: cast emb->fp8, zero flag, and cast W0^T/W1^T to bf16 (for the
// LDS-free gemm phases of the mega-kernel).
__global__ __launch_bounds__(1024) void k_part(
                       const int* __restrict__ src, const int* __restrict__ dst,
                       int E, unsigned int* __restrict__ partbuf,
                       int* __restrict__ cntAB, int partN,
                       const float* __restrict__ emb,
                       unsigned char* __restrict__ embf8, int n4,
                       unsigned char* __restrict__ flag, int N,
                       const float* __restrict__ W0, const float* __restrict__ W1,
                       unsigned short* __restrict__ wt0,
                       unsigned short* __restrict__ wt1) {
    __shared__ int lcnt[SEG];
    int tid = threadIdx.x;
    if (blockIdx.x < PART_W) {
        for (int i = tid; i < SEG; i += 1024) lcnt[i] = 0;
        __syncthreads();
        int w = blockIdx.x;
        int chunk = (E + PART_W - 1) / PART_W;
        int e0 = w * chunk;
        int e1 = e0 + chunk; if (e1 > E) e1 = E;
        for (int e = e0 + tid; e < e1; e += 1024) {
            int d = dst[e];
            int s = src[e];
            int seg = d / partN;
            int dloc = d - seg * partN;
            unsigned int pack = (unsigned int)s | ((unsigned int)dloc << 17);
            int slot = atomicAdd(&lcnt[seg], 1);          // LDS atomic
            if (slot < PSTRIDE)
                partbuf[((size_t)seg * PART_W + w) * PSTRIDE + slot] = pack;
        }
        __syncthreads();
        for (int i = tid; i < SEG; i += 1024) {
            int c = lcnt[i];
            cntAB[i * PART_W + w] = c < PSTRIDE ? c : PSTRIDE;
        }
    } else if (blockIdx.x < PART_W + CAST_BLOCKS) {
        int i0 = (blockIdx.x - PART_W) * 1024 + tid;
        for (int i = i0; i < n4; i += CAST_BLOCKS * 1024) {
            float4 v = ((const float4*)emb)[i];
            int lo = __builtin_amdgcn_cvt_pk_fp8_f32(v.x * XSCALE, v.y * XSCALE, 0, false);
            int pk = __builtin_amdgcn_cvt_pk_fp8_f32(v.z * XSCALE, v.w * XSCALE, lo, true);
            ((int*)embf8)[i] = pk;   // 4 fp8 bytes per thread, coalesced
        }
    } else if (blockIdx.x < PART_W + CAST_BLOCKS + FLAG_BLOCKS) {
        // zero flag[0..N): int4 stores (flag is 256B-aligned workspace)
        int i0 = (blockIdx.x - PART_W - CAST_BLOCKS) * 1024 + tid;
        int n16 = N >> 4;
        for (int i = i0; i < n16; i += FLAG_BLOCKS * 1024) {
            ((int4*)flag)[i] = make_int4(0, 0, 0, 0);
        }
        if (blockIdx.x == PART_W + CAST_BLOCKS && tid < (N & 15))
            flag[(n16 << 4) + tid] = 0;
    } else {
        // W^T bf16 cast: wt[n*128+k] = bf16(W[k*128+n]); 16K elems each
        for (int i = tid; i < HDIM * HDIM; i += 1024) {
            int n = i >> 7, k = i & 127;
            wt0[i] = f2bf(W0[(size_t)k * HDIM + n]);
            wt1[i] = f2bf(W1[(size_t)k * HDIM + n]);
        }
    }
}

// one wg per segment; 16 groups of 16 lanes drain sub-buckets; counts
// preloaded + shfl broadcast. Rider blocks: flag[seq[p]]=1 scatter.
#define PFLAG_BLOCKS 16
__global__ void k_place(const unsigned int* __restrict__ partbuf,
                        const int* __restrict__ cntAB,
                        int* __restrict__ adjB, int* __restrict__ cnt,
                        float* __restrict__ dinv, int partN, int N,
                        const int* __restrict__ seqp, int P,
                        unsigned char* __restrict__ flag) {
    __shared__ int lcur[256];    // partN <= 256
    int tid = threadIdx.x;
    if (blockIdx.x >= SEG) {
        int i0 = (blockIdx.x - SEG) * 256 + tid;
        for (int p = i0; p < P; p += PFLAG_BLOCKS * 256) {
            int sv = seqp[p];
            if (sv >= 0) flag[sv] = 1;
        }
        return;
    }
    int s = blockIdx.x;          // segment id
    for (int i = tid; i < partN; i += 256) lcur[i] = 0;
    __syncthreads();
    int g = tid >> 4;            // group 0..15
    int l16 = tid & 15;          // lane within group
    int cpre = cntAB[s * PART_W + g + 16 * l16];
    const unsigned int* segbuf = partbuf + (size_t)s * PART_W * PSTRIDE;
#pragma unroll 4
    for (int k = 0; k < 16; ++k) {
        int c = __shfl(cpre, k, 16);
        int w = g + 16 * k;
        const unsigned int* sb = segbuf + w * PSTRIDE;
        for (int idx = l16; idx < c; idx += 16) {
            unsigned int v = sb[idx];
            int sv = (int)(v & 0x1FFFFu);
            int dloc = (int)(v >> 17);
            int slot = atomicAdd(&lcur[dloc], 1);          // LDS atomic
            if (slot < BSTRIDE)
                adjB[((size_t)s * partN + dloc) * BSTRIDE + slot] = sv;
        }
    }
    __syncthreads();
    for (int i = tid; i < partN; i += 256) {
        int d = s * partN + i;
        if (d < N) {
            int c = lcur[i];
            cnt[d] = c;                                    // true degree
            dinv[d] = rsqrtf((float)c + 1.0f);
        }
    }
}

// --- R9-proven pull body (one row per wave, 4 groups x 16 lanes, wide row
// loads, scalar nbr loads, unroll-2 with t/t+4, cross-group shfl reduce).
template <int FP8, int SPARSE>
__device__ __forceinline__ void pull_quad(
        int qd, const void* __restrict__ xv, const int* __restrict__ cnt,
        const int* __restrict__ adjB, const float* __restrict__ dinv,
        unsigned short* __restrict__ agg, int N,
        const unsigned char* __restrict__ flag, int tid) {
    int row = qd * 4 + (tid >> 6);
    if (row >= N) return;
    if (SPARSE && !flag[row]) return;
    int lane = tid & 63;
    int g = lane >> 4, l16 = lane & 15;
    int d = cnt[row];
    if (d > BSTRIDE) d = BSTRIDE;
    const int* nbr = adjB + (size_t)row * BSTRIDE;
    float dr = dinv[row];
    const unsigned char* x8 = (const unsigned char*)xv;
    size_t rbytes = FP8 ? HDIM : HDIM * 2;
    unsigned int boff = (FP8 ? 8u : 16u) * (unsigned int)l16;

    float acc[8];
    {   // self term: weight dr*dr in group 0 only
        float sc = (g == 0) ? dr * dr : 0.0f;
        const unsigned char* p = x8 + (size_t)(unsigned)row * rbytes + boff;
        if (FP8) {
            uint2 u = *(const uint2*)p;
            f32x2 f0 = __builtin_amdgcn_cvt_pk_f32_fp8((int)u.x, false);
            f32x2 f1 = __builtin_amdgcn_cvt_pk_f32_fp8((int)u.x, true);
            f32x2 f2 = __builtin_amdgcn_cvt_pk_f32_fp8((int)u.y, false);
            f32x2 f3 = __builtin_amdgcn_cvt_pk_f32_fp8((int)u.y, true);
            acc[0] = f0.x * sc; acc[1] = f0.y * sc;
            acc[2] = f1.x * sc; acc[3] = f1.y * sc;
            acc[4] = f2.x * sc; acc[5] = f2.y * sc;
            acc[6] = f3.x * sc; acc[7] = f3.y * sc;
        } else {
            uint4 u = *(const uint4*)p;
            acc[0] = bf2f((unsigned short)u.x) * sc;
            acc[1] = bf2f((unsigned short)(u.x >> 16)) * sc;
            acc[2] = bf2f((unsigned short)u.y) * sc;
            acc[3] = bf2f((unsigned short)(u.y >> 16)) * sc;
            acc[4] = bf2f((unsigned short)u.z) * sc;
            acc[5] = bf2f((unsigned short)(u.z >> 16)) * sc;
            acc[6] = bf2f((unsigned short)u.w) * sc;
            acc[7] = bf2f((unsigned short)(u.w >> 16)) * sc;
        }
    }
    int t = g;
    for (; t + 4 < d; t += 8) {
        int s0 = nbr[t], s1 = nbr[t + 4];
        float n0 = dinv[s0] * dr, n1 = dinv[s1] * dr;
        const unsigned char* p0 = x8 + (size_t)(unsigned)s0 * rbytes + boff;
        const unsigned char* p1 = x8 + (size_t)(unsigned)s1 * rbytes + boff;
        if (FP8) {
            uint2 a = *(const uint2*)p0;
            uint2 b = *(const uint2*)p1;
            f32x2 a0 = __builtin_amdgcn_cvt_pk_f32_fp8((int)a.x, false);
            f32x2 a1 = __builtin_amdgcn_cvt_pk_f32_fp8((int)a.x, true);
            f32x2 a2 = __builtin_amdgcn_cvt_pk_f32_fp8((int)a.y, false);
            f32x2 a3 = __builtin_amdgcn_cvt_pk_f32_fp8((int)a.y, true);
            acc[0] = fmaf(a0.x, n0, acc[0]); acc[1] = fmaf(a0.y, n0, acc[1]);
            acc[2] = fmaf(a1.x, n0, acc[2]); acc[3] = fmaf(a1.y, n0, acc[3]);
            acc[4] = fmaf(a2.x, n0, acc[4]); acc[5] = fmaf(a2.y, n0, acc[5]);
            acc[6] = fmaf(a3.x, n0, acc[6]); acc[7] = fmaf(a3.y, n0, acc[7]);
            f32x2 b0 = __builtin_amdgcn_cvt_pk_f32_fp8((int)b.x, false);
            f32x2 b1 = __builtin_amdgcn_cvt_pk_f32_fp8((int)b.x, true);
            f32x2 b2 = __builtin_amdgcn_cvt_pk_f32_fp8((int)b.y, false);
            f32x2 b3 = __builtin_amdgcn_cvt_pk_f32_fp8((int)b.y, true);
            acc[0] = fmaf(b0.x, n1, acc[0]); acc[1] = fmaf(b0.y, n1, acc[1]);
            acc[2] = fmaf(b1.x, n1, acc[2]); acc[3] = fmaf(b1.y, n1, acc[3]);
            acc[4] = fmaf(b2.x, n1, acc[4]); acc[5] = fmaf(b2.y, n1, acc[5]);
            acc[6] = fmaf(b3.x, n1, acc[6]); acc[7] = fmaf(b3.y, n1, acc[7]);
        } else {
            uint4 a = *(const uint4*)p0;
            uint4 b = *(const uint4*)p1;
            acc[0] = fmaf(bf2f((unsigned short)a.x),         n0, acc[0]);
            acc[1] = fmaf(bf2f((unsigned short)(a.x >> 16)), n0, acc[1]);
            acc[2] = fmaf(bf2f((unsigned short)a.y),         n0, acc[2]);
            acc[3] = fmaf(bf2f((unsigned short)(a.y >> 16)), n0, acc[3]);
            acc[4] = fmaf(bf2f((unsigned short)a.z),         n0, acc[4]);
            acc[5] = fmaf(bf2f((unsigned short)(a.z >> 16)), n0, acc[5]);
            acc[6] = fmaf(bf2f((unsigned short)a.w),         n0, acc[6]);
            acc[7] = fmaf(bf2f((unsigned short)(a.w >> 16)), n0, acc[7]);
            acc[0] = fmaf(bf2f((unsigned short)b.x),         n1, acc[0]);
            acc[1] = fmaf(bf2f((unsigned short)(b.x >> 16)), n1, acc[1]);
            acc[2] = fmaf(bf2f((unsigned short)b.y),         n1, acc[2]);
            acc[3] = fmaf(bf2f((unsigned short)(b.y >> 16)), n1, acc[3]);
            acc[4] = fmaf(bf2f((unsigned short)b.z),         n1, acc[4]);
            acc[5] = fmaf(bf2f((unsigned short)(b.z >> 16)), n1, acc[5]);
            acc[6] = fmaf(bf2f((unsigned short)b.w),         n1, acc[6]);
            acc[7] = fmaf(bf2f((unsigned short)(b.w >> 16)), n1, acc[7]);
        }
    }
    if (t < d) {
        int s0 = nbr[t];
        float n0 = dinv[s0] * dr;
        const unsigned char* p0 = x8 + (size_t)(unsigned)s0 * rbytes + boff;
        if (FP8) {
            uint2 a = *(const uint2*)p0;
            f32x2 a0 = __builtin_amdgcn_cvt_pk_f32_fp8((int)a.x, false);
            f32x2 a1 = __builtin_amdgcn_cvt_pk_f32_fp8((int)a.x, true);
            f32x2 a2 = __builtin_amdgcn_cvt_pk_f32_fp8((int)a.y, false);
            f32x2 a3 = __builtin_amdgcn_cvt_pk_f32_fp8((int)a.y, true);
            acc[0] = fmaf(a0.x, n0, acc[0]); acc[1] = fmaf(a0.y, n0, acc[1]);
            acc[2] = fmaf(a1.x, n0, acc[2]); acc[3] = fmaf(a1.y, n0, acc[3]);
            acc[4] = fmaf(a2.x, n0, acc[4]); acc[5] = fmaf(a2.y, n0, acc[5]);
            acc[6] = fmaf(a3.x, n0, acc[6]); acc[7] = fmaf(a3.y, n0, acc[7]);
        } else {
            uint4 a = *(const uint4*)p0;
            acc[0] = fmaf(bf2f((unsigned short)a.x),         n0, acc[0]);
            acc[1] = fmaf(bf2f((unsigned short)(a.x >> 16)), n0, acc[1]);
            acc[2] = fmaf(bf2f((unsigned short)a.y),         n0, acc[2]);
            acc[3] = fmaf(bf2f((unsigned short)(a.y >> 16)), n0, acc[3]);
            acc[4] = fmaf(bf2f((unsigned short)a.z),         n0, acc[4]);
            acc[5] = fmaf(bf2f((unsigned short)(a.z >> 16)), n0, acc[5]);
            acc[6] = fmaf(bf2f((unsigned short)a.w),         n0, acc[6]);
            acc[7] = fmaf(bf2f((unsigned short)(a.w >> 16)), n0, acc[7]);
        }
    }
#pragma unroll
    for (int i = 0; i < 8; ++i) {
        acc[i] += __shfl_xor(acc[i], 16);
        acc[i] += __shfl_xor(acc[i], 32);
    }
    if (g == 0) {
        unsigned int w0 = (unsigned int)f2bf(acc[0]) | ((unsigned int)f2bf(acc[1]) << 16);
        unsigned int w1 = (unsigned int)f2bf(acc[2]) | ((unsigned int)f2bf(acc[3]) << 16);
        unsigned int w2 = (unsigned int)f2bf(acc[4]) | ((unsigned int)f2bf(acc[5]) << 16);
        unsigned int w3 = (unsigned int)f2bf(acc[6]) | ((unsigned int)f2bf(acc[7]) << 16);
        uint4 o = make_uint4(w0, w1, w2, w3);
        *(uint4*)(agg + (size_t)(unsigned)row * HDIM + 8u * (unsigned int)l16) = o;
    }
}

// --- LDS-free gemm chunk: B-fragments straight from L2-resident bf16 W^T.
template <int RELU>
__device__ __forceinline__ void gemm_chunk(
        int c, const unsigned short* __restrict__ A,
        const unsigned short* __restrict__ WT, const float* __restrict__ bias,
        float bscale, unsigned short* __restrict__ out, int N, int tid) {
    int lane = tid & 63;
    int wv = tid >> 6;
    int n15 = lane & 15, q = lane >> 4;
    int row0 = c * 64 + wv * 16;
    const unsigned short* arow = A + (size_t)(row0 + n15) * HDIM + q * 8;
    bf16x8 a0 = *(const bf16x8*)(arow);
    bf16x8 a1 = *(const bf16x8*)(arow + 32);
    bf16x8 a2 = *(const bf16x8*)(arow + 64);
    bf16x8 a3 = *(const bf16x8*)(arow + 96);
#pragma unroll
    for (int ct = 0; ct < 8; ++ct) {
        const unsigned short* wrow = WT + (size_t)(ct * 16 + n15) * HDIM + q * 8;
        f32x4 acc = {0.f, 0.f, 0.f, 0.f};
        acc = __builtin_amdgcn_mfma_f32_16x16x32_bf16(a0, *(const bf16x8*)(wrow),      acc, 0, 0, 0);
        acc = __builtin_amdgcn_mfma_f32_16x16x32_bf16(a1, *(const bf16x8*)(wrow + 32), acc, 0, 0, 0);
        acc = __builtin_amdgcn_mfma_f32_16x16x32_bf16(a2, *(const bf16x8*)(wrow + 64), acc, 0, 0, 0);
        acc = __builtin_amdgcn_mfma_f32_16x16x32_bf16(a3, *(const bf16x8*)(wrow + 96), acc, 0, 0, 0);
        float bv = bscale * bias[ct * 16 + n15];
#pragma unroll
        for (int r = 0; r < 4; ++r) {
            int row = row0 + q * 4 + r;
            if (row < N) {
                float v = acc[r] + bv;
                if (RELU) v = fmaxf(v, 0.0f);
                out[(size_t)row * HDIM + ct * 16 + n15] = f2bf(v);
            }
        }
    }
}

// --- fused gemm2+gather chunk in position space (R10-proven logic, LDS-free).
__device__ __forceinline__ void out_chunk(
        int c, const int* __restrict__ seq, int P,
        const unsigned short* __restrict__ A,   // agg2, 16x-scaled
        const unsigned short* __restrict__ WT, const float* __restrict__ bias,
        const float* __restrict__ emb, int N, float* __restrict__ out, int tid) {
    int lane = tid & 63;
    int wv = tid >> 6;
    int n15 = lane & 15, q = lane >> 4;
    int p0 = c * 64 + wv * 16;
    int pp = p0 + n15;
    int svA = (pp < P) ? seq[pp] : 0;
    int arowIdx = (svA >= 0) ? svA : 0;   // specials: dummy row 0 (masked)
    const unsigned short* arow = A + (size_t)arowIdx * HDIM + q * 8;
    bf16x8 a0 = *(const bf16x8*)(arow);
    bf16x8 a1 = *(const bf16x8*)(arow + 32);
    bf16x8 a2 = *(const bf16x8*)(arow + 64);
    bf16x8 a3 = *(const bf16x8*)(arow + 96);
    int posr[4], svr[4];
#pragma unroll
    for (int r = 0; r < 4; ++r) {
        posr[r] = p0 + q * 4 + r;
        svr[r] = (posr[r] < P) ? seq[posr[r]] : 0;
    }
#pragma unroll
    for (int ct = 0; ct < 8; ++ct) {
        const unsigned short* wrow = WT + (size_t)(ct * 16 + n15) * HDIM + q * 8;
        f32x4 acc = {0.f, 0.f, 0.f, 0.f};
        acc = __builtin_amdgcn_mfma_f32_16x16x32_bf16(a0, *(const bf16x8*)(wrow),      acc, 0, 0, 0);
        acc = __builtin_amdgcn_mfma_f32_16x16x32_bf16(a1, *(const bf16x8*)(wrow + 32), acc, 0, 0, 0);
        acc = __builtin_amdgcn_mfma_f32_16x16x32_bf16(a2, *(const bf16x8*)(wrow + 64), acc, 0, 0, 0);
        acc = __builtin_amdgcn_mfma_f32_16x16x32_bf16(a3, *(const bf16x8*)(wrow + 96), acc, 0, 0, 0);
        float bv = bias[ct * 16 + n15];
#pragma unroll
        for (int r = 0; r < 4; ++r) {
            if (posr[r] < P) {
                int sv = svr[r];
                float v;
                if (sv >= 0) {
                    v = acc[r] * XINV + bv;
                } else {
                    v = emb[(size_t)(sv + OFF_SPECIAL + N) * HDIM + ct * 16 + n15];
                }
                out[(size_t)posr[r] * HDIM + ct * 16 + n15] = v;
            }
        }
    }
}

// --- cooperative mega-kernel: pull1 -> gemm1 -> pull2 -> out, 3 grid syncs.
// Zero LDS (W^T from L2) so every phase runs at full occupancy; 3 enqueue
// gaps deleted. grid.sync() provides device-scope visibility across XCDs.
__global__ __launch_bounds__(256, 6) void k_mega(
        const unsigned char* __restrict__ embf8,
        const unsigned short* __restrict__ wt0,
        const unsigned short* __restrict__ wt1,
        const float* __restrict__ b0, const float* __restrict__ b1,
        const int* __restrict__ cnt, const int* __restrict__ adjB,
        const float* __restrict__ dinv,
        unsigned short* __restrict__ aggbf, unsigned short* __restrict__ hbuf,
        const unsigned char* __restrict__ flag,
        const int* __restrict__ seq, int P,
        const float* __restrict__ emb, float* __restrict__ out, int N) {
    cg::grid_group grid = cg::this_grid();
    int tid = threadIdx.x;
    int nb = gridDim.x;
    int nQuads = (N + 3) >> 2;
    // phase 1: conv1 pull (fp8 dense) -> agg1 = aggbf
    for (int qd = blockIdx.x; qd < nQuads; qd += nb)
        pull_quad<1, 0>(qd, embf8, cnt, adjB, dinv, aggbf, N, nullptr, tid);
    grid.sync();
    // phase 2: gemm1 + ReLU (bias*16) -> h = hbuf (overwrites dead embf8)
    int nChunks = (N + 63) / 64;
    for (int c = blockIdx.x; c < nChunks; c += nb)
        gemm_chunk<1>(c, aggbf, wt0, b0, XSCALE, hbuf, N, tid);
    grid.sync();
    // phase 3: conv2 pull (bf16, flag-sparse ~26%) -> agg2 = aggbf (in place
    // over agg1; unflagged rows keep stale agg1, never read by phase 4)
    for (int qd = blockIdx.x; qd < nQuads; qd += nb)
        pull_quad<0, 1>(qd, hbuf, cnt, adjB, dinv, aggbf, N, flag, tid);
    grid.sync();
    // phase 4: fused gemm2+gather in position space
    int oChunks = (P + 63) / 64;
    for (int c = blockIdx.x; c < oChunks; c += nb)
        out_chunk(c, seq, P, aggbf, wt1, b1, emb, N, out, tid);
}

extern "C" void kernel_launch(void* const* d_in, const int* in_sizes, int n_in,
                              void* d_out, int out_size, void* d_ws, size_t ws_size,
                              hipStream_t stream) {
    const float* emb = (const float*)d_in[0];
    const float* W0  = (const float*)d_in[1];
    const float* b0  = (const float*)d_in[2];
    const float* W1  = (const float*)d_in[3];
    const float* b1  = (const float*)d_in[4];
    const int* ei  = (const int*)d_in[5];
    const int* seq = (const int*)d_in[6];

    int N = in_sizes[0] / HDIM - OFF_SPECIAL;   // 100000
    int E = in_sizes[5] / 2;                    // 1600000
    int P = in_sizes[6];                        // 32768
    const int* srcp = ei;
    const int* dstp = ei + E;

    // workspace (~71 MB), lifecycle:
    //   aggbf (25.6): partbuf alias (dead after k_place) -> agg1 -> agg2.
    //   buf1 (25.6): embf8 (12.8 low) + cntAB (512K @ +16MB) -> h.
    //   wt0/wt1 (32 KB each): bf16 W^T for the LDS-free gemm phases.
    char* ws = (char*)d_ws;
    size_t off = 0;
    auto alloc = [&](size_t bytes) {
        void* p = ws + off;
        off = (off + bytes + 255) & ~(size_t)255;
        return p;
    };
    unsigned short* aggbf = (unsigned short*)alloc((size_t)N * HDIM * sizeof(unsigned short));
    unsigned short* buf1  = (unsigned short*)alloc((size_t)N * HDIM * sizeof(unsigned short));
    int*   adjB = (int*)alloc((size_t)N * BSTRIDE * sizeof(int));
    int*   cnt  = (int*)alloc((size_t)N * sizeof(int));
    unsigned char* flag = (unsigned char*)alloc((size_t)N);
    float* dinv = (float*)alloc((size_t)N * sizeof(float));
    unsigned short* wt0 = (unsigned short*)alloc((size_t)HDIM * HDIM * sizeof(unsigned short));
    unsigned short* wt1 = (unsigned short*)alloc((size_t)HDIM * HDIM * sizeof(unsigned short));
    unsigned int* partbuf = (unsigned int*)aggbf;
    unsigned char* embf8  = (unsigned char*)buf1;
    int* cntAB = (int*)((char*)buf1 + 16u * 1024u * 1024u);  // dead zone of buf1

    int partN = (N + SEG - 1) / SEG;              // 200 for N=100000 (<=256)
    int n4 = N * HDIM / 4;
    k_part<<<PART_W + CAST_BLOCKS + FLAG_BLOCKS + 1, 1024, 0, stream>>>(
        srcp, dstp, E, partbuf, cntAB, partN, emb, embf8, n4, flag, N,
        W0, W1, wt0, wt1);
    k_place<<<SEG + PFLAG_BLOCKS, 256, 0, stream>>>(
        partbuf, cntAB, adjB, cnt, dinv, partN, N, seq, P, flag);

    // cooperative mega-kernel: grid sized to guaranteed co-residency
    int maxBlocksPerCU = 0;
    hipOccupancyMaxActiveBlocksPerMultiprocessor(&maxBlocksPerCU,
                                                 (const void*)k_mega, 256, 0);
    if (maxBlocksPerCU < 1) maxBlocksPerCU = 1;
    int megaGrid = maxBlocksPerCU * 256;          // 256 CUs
    int nQuads = (N + 3) >> 2;
    if (megaGrid > nQuads) megaGrid = nQuads;

    float* outp = (float*)d_out;
    void* args[] = {
        (void*)&embf8, (void*)&wt0, (void*)&wt1, (void*)&b0, (void*)&b1,
        (void*)&cnt, (void*)&adjB, (void*)&dinv, (void*)&aggbf, (void*)&buf1,
        (void*)&flag, (void*)&seq, (void*)&P, (void*)&emb, (void*)&outp,
        (void*)&N
    };
    hipLaunchCooperativeKernel((const void*)k_mega, dim3(megaGrid), dim3(256),
                               args, 0, stream);
}

// Round 13
// 270.041 us; speedup vs baseline: 2.5451x; 2.5451x over previous
//
#include <hip/hip_runtime.h>

#define HDIM 128
#define OFF_SPECIAL 2
#define BSTRIDE 48   // bucket slots per node; deg~Poisson(16), P(deg>=48)~5e-11

typedef __attribute__((ext_vector_type(8))) short bf16x8;
typedef __attribute__((ext_vector_type(4))) float f32x4;
typedef __attribute__((ext_vector_type(2))) float f32x2;

__device__ __forceinline__ float bf2f(unsigned short u) {
    union { unsigned int i; float f; } v;
    v.i = ((unsigned int)u) << 16;
    return v.f;
}
__device__ __forceinline__ unsigned short f2bf(float f) {
    union { float f; unsigned int i; } v;
    v.f = f;
    unsigned int x = v.i;
    x += 0x7FFFu + ((x >> 16) & 1u);   // RNE; data has no NaNs
    return (unsigned short)(x >> 16);
}

// Scale folding for the fp8 emb cast: embf8 = q(16*emb). ReLU is positively
// homogeneous, so conv1 yields 16h (bias*16); conv2's agg2 is 16-scaled and
// k_out applies acc*(1/16) + b1 directly (exact power-of-2 folding).
#define XSCALE 16.0f
#define XINV   0.0625f

// --- radix-partition CSR build (R7/R11-proven): ZERO global atomics.
// R12 lesson (with R8): any structure that cuts resident wave count to save
// launches/traffic loses — the pulls need ~25k cheap blocks to hide gather
// latency. Cooperative mega-kernel ran at 5% VALU; do not retry.
#define SEG 500
#define PSTRIDE 48    // per-(wg,seg) bucket cap; Poisson(12.5), P(ovf)~1e-13
#define PART_W 256
#define CAST_BLOCKS 128   // x1024 threads
#define FLAG_BLOCKS 4

// riders: cast emb->fp8, and ZERO the flag array (scatter rides on k_place;
// order zero -> scatter -> use holds across the kernel sequence).
__global__ __launch_bounds__(1024) void k_part(
                       const int* __restrict__ src, const int* __restrict__ dst,
                       int E, unsigned int* __restrict__ partbuf,
                       int* __restrict__ cntAB, int partN,
                       const float* __restrict__ emb,
                       unsigned char* __restrict__ embf8, int n4,
                       unsigned char* __restrict__ flag, int N) {
    __shared__ int lcnt[SEG];
    int tid = threadIdx.x;
    if (blockIdx.x < PART_W) {
        for (int i = tid; i < SEG; i += 1024) lcnt[i] = 0;
        __syncthreads();
        int w = blockIdx.x;
        int chunk = (E + PART_W - 1) / PART_W;
        int e0 = w * chunk;
        int e1 = e0 + chunk; if (e1 > E) e1 = E;
        for (int e = e0 + tid; e < e1; e += 1024) {
            int d = dst[e];
            int s = src[e];
            int seg = d / partN;
            int dloc = d - seg * partN;
            unsigned int pack = (unsigned int)s | ((unsigned int)dloc << 17);
            int slot = atomicAdd(&lcnt[seg], 1);          // LDS atomic
            if (slot < PSTRIDE)
                partbuf[((size_t)seg * PART_W + w) * PSTRIDE + slot] = pack;
        }
        __syncthreads();
        for (int i = tid; i < SEG; i += 1024) {
            int c = lcnt[i];
            cntAB[i * PART_W + w] = c < PSTRIDE ? c : PSTRIDE;
        }
    } else if (blockIdx.x < PART_W + CAST_BLOCKS) {
        int i0 = (blockIdx.x - PART_W) * 1024 + tid;
        for (int i = i0; i < n4; i += CAST_BLOCKS * 1024) {
            float4 v = ((const float4*)emb)[i];
            int lo = __builtin_amdgcn_cvt_pk_fp8_f32(v.x * XSCALE, v.y * XSCALE, 0, false);
            int pk = __builtin_amdgcn_cvt_pk_fp8_f32(v.z * XSCALE, v.w * XSCALE, lo, true);
            ((int*)embf8)[i] = pk;   // 4 fp8 bytes per thread, coalesced
        }
    } else {
        // zero flag[0..N): int4 stores (flag is 256B-aligned workspace)
        int i0 = (blockIdx.x - PART_W - CAST_BLOCKS) * 1024 + tid;
        int n16 = N >> 4;
        for (int i = i0; i < n16; i += FLAG_BLOCKS * 1024) {
            ((int4*)flag)[i] = make_int4(0, 0, 0, 0);
        }
        if (blockIdx.x == PART_W + CAST_BLOCKS && tid < (N & 15))
            flag[(n16 << 4) + tid] = 0;
    }
}

// one wg per segment; 16 groups of 16 lanes drain sub-buckets; counts
// preloaded + shfl broadcast. Rider blocks: flag[seq[p]]=1 scatter.
#define PFLAG_BLOCKS 16
__global__ void k_place(const unsigned int* __restrict__ partbuf,
                        const int* __restrict__ cntAB,
                        int* __restrict__ adjB, int* __restrict__ cnt,
                        float* __restrict__ dinv, int partN, int N,
                        const int* __restrict__ seqp, int P,
                        unsigned char* __restrict__ flag) {
    __shared__ int lcur[256];    // partN <= 256
    int tid = threadIdx.x;
    if (blockIdx.x >= SEG) {
        int i0 = (blockIdx.x - SEG) * 256 + tid;
        for (int p = i0; p < P; p += PFLAG_BLOCKS * 256) {
            int sv = seqp[p];
            if (sv >= 0) flag[sv] = 1;
        }
        return;
    }
    int s = blockIdx.x;          // segment id
    for (int i = tid; i < partN; i += 256) lcur[i] = 0;
    __syncthreads();
    int g = tid >> 4;            // group 0..15
    int l16 = tid & 15;          // lane within group
    int cpre = cntAB[s * PART_W + g + 16 * l16];
    const unsigned int* segbuf = partbuf + (size_t)s * PART_W * PSTRIDE;
#pragma unroll 4
    for (int k = 0; k < 16; ++k) {
        int c = __shfl(cpre, k, 16);
        int w = g + 16 * k;
        const unsigned int* sb = segbuf + w * PSTRIDE;
        for (int idx = l16; idx < c; idx += 16) {
            unsigned int v = sb[idx];
            int sv = (int)(v & 0x1FFFFu);
            int dloc = (int)(v >> 17);
            int slot = atomicAdd(&lcur[dloc], 1);          // LDS atomic
            if (slot < BSTRIDE)
                adjB[((size_t)s * partN + dloc) * BSTRIDE + slot] = sv;
        }
    }
    __syncthreads();
    for (int i = tid; i < partN; i += 256) {
        int d = s * partN + i;
        if (d < N) {
            int c = lcur[i];
            cnt[d] = c;                                    // true degree
            dinv[d] = rsqrtf((float)c + 1.0f);
        }
    }
}

// --- pull-conv (R9-proven, the 55.5us loop — R11's pair-load variant
// regressed and is reverted): one row per wave, 4 groups of 16 lanes, each
// group one neighbor per iteration with wide loads (fp8 8B, bf16 16B);
// cross-group shfl reduce; group 0 stores. SPARSE=1: flagged rows only.
template <int FP8, int SPARSE>
__global__ __launch_bounds__(256, 8) void k_pull(
        const void* __restrict__ xv, const int* __restrict__ cnt,
        const int* __restrict__ adjB, const float* __restrict__ dinv,
        unsigned short* __restrict__ agg, int N,
        const unsigned char* __restrict__ flag) {
    int row = blockIdx.x * 4 + (threadIdx.x >> 6);
    if (row >= N) return;
    if (SPARSE && !flag[row]) return;
    int lane = threadIdx.x & 63;
    int g = lane >> 4, l16 = lane & 15;
    int d = cnt[row];
    if (d > BSTRIDE) d = BSTRIDE;
    const int* nbr = adjB + (size_t)row * BSTRIDE;
    float dr = dinv[row];
    const unsigned char* x8 = (const unsigned char*)xv;
    size_t rbytes = FP8 ? HDIM : HDIM * 2;
    unsigned int boff = (FP8 ? 8u : 16u) * (unsigned int)l16;

    float acc[8];
    {   // self term: weight dr*dr in group 0 only (reduce then counts it once)
        float sc = (g == 0) ? dr * dr : 0.0f;
        const unsigned char* p = x8 + (size_t)(unsigned)row * rbytes + boff;
        if (FP8) {
            uint2 u = *(const uint2*)p;
            f32x2 f0 = __builtin_amdgcn_cvt_pk_f32_fp8((int)u.x, false);
            f32x2 f1 = __builtin_amdgcn_cvt_pk_f32_fp8((int)u.x, true);
            f32x2 f2 = __builtin_amdgcn_cvt_pk_f32_fp8((int)u.y, false);
            f32x2 f3 = __builtin_amdgcn_cvt_pk_f32_fp8((int)u.y, true);
            acc[0] = f0.x * sc; acc[1] = f0.y * sc;
            acc[2] = f1.x * sc; acc[3] = f1.y * sc;
            acc[4] = f2.x * sc; acc[5] = f2.y * sc;
            acc[6] = f3.x * sc; acc[7] = f3.y * sc;
        } else {
            uint4 u = *(const uint4*)p;
            acc[0] = bf2f((unsigned short)u.x) * sc;
            acc[1] = bf2f((unsigned short)(u.x >> 16)) * sc;
            acc[2] = bf2f((unsigned short)u.y) * sc;
            acc[3] = bf2f((unsigned short)(u.y >> 16)) * sc;
            acc[4] = bf2f((unsigned short)u.z) * sc;
            acc[5] = bf2f((unsigned short)(u.z >> 16)) * sc;
            acc[6] = bf2f((unsigned short)u.w) * sc;
            acc[7] = bf2f((unsigned short)(u.w >> 16)) * sc;
        }
    }
    // group g owns neighbors t = g, g+4, g+8, ... ; unroll 2 (t, t+4)
    int t = g;
    for (; t + 4 < d; t += 8) {
        int s0 = nbr[t], s1 = nbr[t + 4];
        float n0 = dinv[s0] * dr, n1 = dinv[s1] * dr;
        const unsigned char* p0 = x8 + (size_t)(unsigned)s0 * rbytes + boff;
        const unsigned char* p1 = x8 + (size_t)(unsigned)s1 * rbytes + boff;
        if (FP8) {
            uint2 a = *(const uint2*)p0;
            uint2 b = *(const uint2*)p1;
            f32x2 a0 = __builtin_amdgcn_cvt_pk_f32_fp8((int)a.x, false);
            f32x2 a1 = __builtin_amdgcn_cvt_pk_f32_fp8((int)a.x, true);
            f32x2 a2 = __builtin_amdgcn_cvt_pk_f32_fp8((int)a.y, false);
            f32x2 a3 = __builtin_amdgcn_cvt_pk_f32_fp8((int)a.y, true);
            acc[0] = fmaf(a0.x, n0, acc[0]); acc[1] = fmaf(a0.y, n0, acc[1]);
            acc[2] = fmaf(a1.x, n0, acc[2]); acc[3] = fmaf(a1.y, n0, acc[3]);
            acc[4] = fmaf(a2.x, n0, acc[4]); acc[5] = fmaf(a2.y, n0, acc[5]);
            acc[6] = fmaf(a3.x, n0, acc[6]); acc[7] = fmaf(a3.y, n0, acc[7]);
            f32x2 b0 = __builtin_amdgcn_cvt_pk_f32_fp8((int)b.x, false);
            f32x2 b1 = __builtin_amdgcn_cvt_pk_f32_fp8((int)b.x, true);
            f32x2 b2 = __builtin_amdgcn_cvt_pk_f32_fp8((int)b.y, false);
            f32x2 b3 = __builtin_amdgcn_cvt_pk_f32_fp8((int)b.y, true);
            acc[0] = fmaf(b0.x, n1, acc[0]); acc[1] = fmaf(b0.y, n1, acc[1]);
            acc[2] = fmaf(b1.x, n1, acc[2]); acc[3] = fmaf(b1.y, n1, acc[3]);
            acc[4] = fmaf(b2.x, n1, acc[4]); acc[5] = fmaf(b2.y, n1, acc[5]);
            acc[6] = fmaf(b3.x, n1, acc[6]); acc[7] = fmaf(b3.y, n1, acc[7]);
        } else {
            uint4 a = *(const uint4*)p0;
            uint4 b = *(const uint4*)p1;
            acc[0] = fmaf(bf2f((unsigned short)a.x),         n0, acc[0]);
            acc[1] = fmaf(bf2f((unsigned short)(a.x >> 16)), n0, acc[1]);
            acc[2] = fmaf(bf2f((unsigned short)a.y),         n0, acc[2]);
            acc[3] = fmaf(bf2f((unsigned short)(a.y >> 16)), n0, acc[3]);
            acc[4] = fmaf(bf2f((unsigned short)a.z),         n0, acc[4]);
            acc[5] = fmaf(bf2f((unsigned short)(a.z >> 16)), n0, acc[5]);
            acc[6] = fmaf(bf2f((unsigned short)a.w),         n0, acc[6]);
            acc[7] = fmaf(bf2f((unsigned short)(a.w >> 16)), n0, acc[7]);
            acc[0] = fmaf(bf2f((unsigned short)b.x),         n1, acc[0]);
            acc[1] = fmaf(bf2f((unsigned short)(b.x >> 16)), n1, acc[1]);
            acc[2] = fmaf(bf2f((unsigned short)b.y),         n1, acc[2]);
            acc[3] = fmaf(bf2f((unsigned short)(b.y >> 16)), n1, acc[3]);
            acc[4] = fmaf(bf2f((unsigned short)b.z),         n1, acc[4]);
            acc[5] = fmaf(bf2f((unsigned short)(b.z >> 16)), n1, acc[5]);
            acc[6] = fmaf(bf2f((unsigned short)b.w),         n1, acc[6]);
            acc[7] = fmaf(bf2f((unsigned short)(b.w >> 16)), n1, acc[7]);
        }
    }
    if (t < d) {   // at most one leftover per group
        int s0 = nbr[t];
        float n0 = dinv[s0] * dr;
        const unsigned char* p0 = x8 + (size_t)(unsigned)s0 * rbytes + boff;
        if (FP8) {
            uint2 a = *(const uint2*)p0;
            f32x2 a0 = __builtin_amdgcn_cvt_pk_f32_fp8((int)a.x, false);
            f32x2 a1 = __builtin_amdgcn_cvt_pk_f32_fp8((int)a.x, true);
            f32x2 a2 = __builtin_amdgcn_cvt_pk_f32_fp8((int)a.y, false);
            f32x2 a3 = __builtin_amdgcn_cvt_pk_f32_fp8((int)a.y, true);
            acc[0] = fmaf(a0.x, n0, acc[0]); acc[1] = fmaf(a0.y, n0, acc[1]);
            acc[2] = fmaf(a1.x, n0, acc[2]); acc[3] = fmaf(a1.y, n0, acc[3]);
            acc[4] = fmaf(a2.x, n0, acc[4]); acc[5] = fmaf(a2.y, n0, acc[5]);
            acc[6] = fmaf(a3.x, n0, acc[6]); acc[7] = fmaf(a3.y, n0, acc[7]);
        } else {
            uint4 a = *(const uint4*)p0;
            acc[0] = fmaf(bf2f((unsigned short)a.x),         n0, acc[0]);
            acc[1] = fmaf(bf2f((unsigned short)(a.x >> 16)), n0, acc[1]);
            acc[2] = fmaf(bf2f((unsigned short)a.y),         n0, acc[2]);
            acc[3] = fmaf(bf2f((unsigned short)(a.y >> 16)), n0, acc[3]);
            acc[4] = fmaf(bf2f((unsigned short)a.z),         n0, acc[4]);
            acc[5] = fmaf(bf2f((unsigned short)(a.z >> 16)), n0, acc[5]);
            acc[6] = fmaf(bf2f((unsigned short)a.w),         n0, acc[6]);
            acc[7] = fmaf(bf2f((unsigned short)(a.w >> 16)), n0, acc[7]);
        }
    }
    // cross-group reduce (4 groups -> full sum in every lane)
#pragma unroll
    for (int i = 0; i < 8; ++i) {
        acc[i] += __shfl_xor(acc[i], 16);
        acc[i] += __shfl_xor(acc[i], 32);
    }
    if (g == 0) {
        unsigned int w0 = (unsigned int)f2bf(acc[0]) | ((unsigned int)f2bf(acc[1]) << 16);
        unsigned int w1 = (unsigned int)f2bf(acc[2]) | ((unsigned int)f2bf(acc[3]) << 16);
        unsigned int w2 = (unsigned int)f2bf(acc[4]) | ((unsigned int)f2bf(acc[5]) << 16);
        unsigned int w3 = (unsigned int)f2bf(acc[6]) | ((unsigned int)f2bf(acc[7]) << 16);
        uint4 o = make_uint4(w0, w1, w2, w3);
        *(uint4*)(agg + (size_t)(unsigned)row * HDIM + 8u * (unsigned int)l16) = o;
    }
}

// --- MFMA GEMM (R7-proven, LDS W^T): h = relu(agg1@W0 + 16*b0).
template <int RELU>
__global__ __launch_bounds__(256) void k_gemm_mfma(
        const unsigned short* __restrict__ A, const float* __restrict__ W,
        const float* __restrict__ bias, float bscale,
        unsigned short* __restrict__ out, int N) {
    __shared__ __align__(16) unsigned short Wt[HDIM * 136];  // [n][k], pad->34.8 KB
    int tid = threadIdx.x;
    for (int i = tid; i < HDIM * HDIM; i += 256) {
        int k = i >> 7, n = i & 127;
        Wt[n * 136 + k] = f2bf(W[i]);   // W[k][n] row-major
    }
    int lane = tid & 63;
    int wv = tid >> 6;
    int n15 = lane & 15, q = lane >> 4;
    float bv[8];
#pragma unroll
    for (int ct = 0; ct < 8; ++ct) bv[ct] = bscale * bias[ct * 16 + n15];
    __syncthreads();

    int nChunks = (N + 63) / 64;
    for (int c = blockIdx.x; c < nChunks; c += gridDim.x) {
        int row0 = c * 64 + wv * 16;
        const unsigned short* arow = A + (size_t)(row0 + n15) * HDIM + q * 8;
        bf16x8 a0 = *(const bf16x8*)(arow);
        bf16x8 a1 = *(const bf16x8*)(arow + 32);
        bf16x8 a2 = *(const bf16x8*)(arow + 64);
        bf16x8 a3 = *(const bf16x8*)(arow + 96);
#pragma unroll
        for (int ct = 0; ct < 8; ++ct) {
            const unsigned short* wrow = &Wt[(ct * 16 + n15) * 136 + q * 8];
            f32x4 acc = {0.f, 0.f, 0.f, 0.f};
            acc = __builtin_amdgcn_mfma_f32_16x16x32_bf16(a0, *(const bf16x8*)(wrow),      acc, 0, 0, 0);
            acc = __builtin_amdgcn_mfma_f32_16x16x32_bf16(a1, *(const bf16x8*)(wrow + 32), acc, 0, 0, 0);
            acc = __builtin_amdgcn_mfma_f32_16x16x32_bf16(a2, *(const bf16x8*)(wrow + 64), acc, 0, 0, 0);
            acc = __builtin_amdgcn_mfma_f32_16x16x32_bf16(a3, *(const bf16x8*)(wrow + 96), acc, 0, 0, 0);
#pragma unroll
            for (int r = 0; r < 4; ++r) {
                int row = row0 + q * 4 + r;
                if (row < N) {
                    float v = acc[r] + bv[ct];
                    if (RELU) v = fmaxf(v, 0.0f);
                    out[(size_t)row * HDIM + ct * 16 + n15] = f2bf(v);
                }
            }
        }
    }
}

// --- k_out (R10-proven): fused gemm2 + gather in POSITION space.
// out[p] = (agg2[seq[p]] @ W1)*(1/16) + b1 for nodes; specials copy emb rows.
__global__ __launch_bounds__(256) void k_out(
        const int* __restrict__ seq, int P,
        const unsigned short* __restrict__ A,   // agg2, 16x-scaled
        const float* __restrict__ W, const float* __restrict__ bias,
        const float* __restrict__ emb, int N,
        float* __restrict__ out) {
    __shared__ __align__(16) unsigned short Wt[HDIM * 136];
    int tid = threadIdx.x;
    for (int i = tid; i < HDIM * HDIM; i += 256) {
        int k = i >> 7, n = i & 127;
        Wt[n * 136 + k] = f2bf(W[i]);   // W[k][n] row-major
    }
    int lane = tid & 63;
    int wv = tid >> 6;
    int n15 = lane & 15, q = lane >> 4;
    float bv[8];
#pragma unroll
    for (int ct = 0; ct < 8; ++ct) bv[ct] = bias[ct * 16 + n15];   // unscaled
    __syncthreads();

    int nChunks = (P + 63) / 64;
    for (int c = blockIdx.x; c < nChunks; c += gridDim.x) {
        int p0 = c * 64 + wv * 16;
        int pp = p0 + n15;
        int svA = (pp < P) ? seq[pp] : 0;
        int arowIdx = (svA >= 0) ? svA : 0;   // specials: dummy row 0 (masked)
        const unsigned short* arow = A + (size_t)arowIdx * HDIM + q * 8;
        bf16x8 a0 = *(const bf16x8*)(arow);
        bf16x8 a1 = *(const bf16x8*)(arow + 32);
        bf16x8 a2 = *(const bf16x8*)(arow + 64);
        bf16x8 a3 = *(const bf16x8*)(arow + 96);
        int posr[4], svr[4];
#pragma unroll
        for (int r = 0; r < 4; ++r) {
            posr[r] = p0 + q * 4 + r;
            svr[r] = (posr[r] < P) ? seq[posr[r]] : 0;
        }
#pragma unroll
        for (int ct = 0; ct < 8; ++ct) {
            const unsigned short* wrow = &Wt[(ct * 16 + n15) * 136 + q * 8];
            f32x4 acc = {0.f, 0.f, 0.f, 0.f};
            acc = __builtin_amdgcn_mfma_f32_16x16x32_bf16(a0, *(const bf16x8*)(wrow),      acc, 0, 0, 0);
            acc = __builtin_amdgcn_mfma_f32_16x16x32_bf16(a1, *(const bf16x8*)(wrow + 32), acc, 0, 0, 0);
            acc = __builtin_amdgcn_mfma_f32_16x16x32_bf16(a2, *(const bf16x8*)(wrow + 64), acc, 0, 0, 0);
            acc = __builtin_amdgcn_mfma_f32_16x16x32_bf16(a3, *(const bf16x8*)(wrow + 96), acc, 0, 0, 0);
#pragma unroll
            for (int r = 0; r < 4; ++r) {
                if (posr[r] < P) {
                    int sv = svr[r];
                    float v;
                    if (sv >= 0) {
                        v = acc[r] * XINV + bv[ct];
                    } else {
                        v = emb[(size_t)(sv + OFF_SPECIAL + N) * HDIM + ct * 16 + n15];
                    }
                    out[(size_t)posr[r] * HDIM + ct * 16 + n15] = v;
                }
            }
        }
    }
}

extern "C" void kernel_launch(void* const* d_in, const int* in_sizes, int n_in,
                              void* d_out, int out_size, void* d_ws, size_t ws_size,
                              hipStream_t stream) {
    const float* emb = (const float*)d_in[0];
    const float* W0  = (const float*)d_in[1];
    const float* b0  = (const float*)d_in[2];
    const float* W1  = (const float*)d_in[3];
    const float* b1  = (const float*)d_in[4];
    const int* ei  = (const int*)d_in[5];
    const int* seq = (const int*)d_in[6];

    int N = in_sizes[0] / HDIM - OFF_SPECIAL;   // 100000
    int E = in_sizes[5] / 2;                    // 1600000
    int P = in_sizes[6];                        // 32768
    const int* srcp = ei;
    const int* dstp = ei + E;

    // workspace (~71 MB), lifecycle:
    //   aggbf (25.6): partbuf alias (dead after k_place) -> agg1 (pull1 out,
    //         gemm1 in) -> agg2 (pull2 out) -> k_out A-input.
    //   buf1 (25.6): embf8 (12.8 low) + cntAB (512K @ +16MB) -> h (gemm1 out,
    //         pull2 in; overwrites both dead aliases).
    char* ws = (char*)d_ws;
    size_t off = 0;
    auto alloc = [&](size_t bytes) {
        void* p = ws + off;
        off = (off + bytes + 255) & ~(size_t)255;
        return p;
    };
    unsigned short* aggbf = (unsigned short*)alloc((size_t)N * HDIM * sizeof(unsigned short));
    unsigned short* buf1  = (unsigned short*)alloc((size_t)N * HDIM * sizeof(unsigned short));
    int*   adjB = (int*)alloc((size_t)N * BSTRIDE * sizeof(int));
    int*   cnt  = (int*)alloc((size_t)N * sizeof(int));
    unsigned char* flag = (unsigned char*)alloc((size_t)N);
    float* dinv = (float*)alloc((size_t)N * sizeof(float));
    unsigned int* partbuf = (unsigned int*)aggbf;
    unsigned char* embf8  = (unsigned char*)buf1;
    int* cntAB = (int*)((char*)buf1 + 16u * 1024u * 1024u);  // dead zone of buf1

    int partN = (N + SEG - 1) / SEG;              // 200 for N=100000 (<=256)
    int n4 = N * HDIM / 4;
    k_part<<<PART_W + CAST_BLOCKS + FLAG_BLOCKS, 1024, 0, stream>>>(
        srcp, dstp, E, partbuf, cntAB, partN, emb, embf8, n4, flag, N);
    k_place<<<SEG + PFLAG_BLOCKS, 256, 0, stream>>>(
        partbuf, cntAB, adjB, cnt, dinv, partN, N, seq, P, flag);

    int pullBlocks = (N + 3) / 4;   // 4 waves/block, 1 row/wave

    // conv1 (dense, fp8 input): pull(embf8) -> aggbf; GEMM+ReLU (bias*16) -> h
    k_pull<1, 0><<<pullBlocks, 256, 0, stream>>>(embf8, cnt, adjB, dinv, aggbf, N, nullptr);
    k_gemm_mfma<1><<<640, 256, 0, stream>>>(aggbf, W0, b0, XSCALE, buf1, N);

    // conv2 pull (bf16, sparse ~26%): pull(h=buf1) -> agg2 = aggbf
    k_pull<0, 1><<<pullBlocks, 256, 0, stream>>>(buf1, cnt, adjB, dinv, aggbf, N, flag);

    // fused gemm2+gather in position space
    int outBlocks = (P + 63) / 64;
    k_out<<<outBlocks, 256, 0, stream>>>(seq, P, aggbf, W1, b1, emb, N,
                                         (float*)d_out);
}